// Round 10
// baseline (1817.103 us; speedup 1.0000x reference)
//
#include <hip/hip_runtime.h>
#include <stdint.h>

// Problem constants (fp32 in/out; conv via split-bf16 MFMA with verified fallback)
#define NPOS 2394          // 38*63
#define CIN 512
#define KK 4608            // 512*9
#define NANCH 21546        // NPOS*9
#define PRE 6000
#define POST 300
#define NWORD 94           // ceil(6000/64)
#define NQ 8
#define QLEN 2694          // ceil(21546/8)
#define FEATT_BYTES 4902912   // NPOS*512*4 (fp32 featT, lives in d_ws; ws_ok==true measured R7/R8)

// ---- d_out scratch map (bytes). out bytes = 30,105,600.
#define OFF_P     0
#define OFF_SBOX  0                  // aliases dead P
#define OFF_KEEP  96256
#define OFF_BH    4902912
#define OFF_MASK  4902912            // aliases dead BH
#define OFF_BM    9621504
#define OFF_BL    14340096
#define OFF_FH    19058688
#define OFF_FM    21510144
#define OFF_FL    23961600
#define OFF_KEYS  26413056
#define OFF_PROP  26585600
#define OFF_RPART 26930432
#define OFF_FLAG  27619904

typedef short bf16x8 __attribute__((ext_vector_type(8)));
typedef float f32x4 __attribute__((ext_vector_type(4)));

__device__ __forceinline__ float bf2f(unsigned short u) {
    union { unsigned int i; float f; } v; v.i = ((unsigned int)u) << 16; return v.f;
}
__device__ __forceinline__ unsigned short f2bf(float f) {
    union { float f; unsigned int i; } v; v.f = f;
    unsigned int x = v.i;
    return (unsigned short)((x + 0x7fffu + ((x >> 16) & 1u)) >> 16);   // RNE
}
__device__ __forceinline__ bf16x8 as_bf8(uint4 u) {
    union { uint4 u; bf16x8 b; } c; c.u = u; return c.b;
}

// transpose net (512,2394) -> featT fp32 (2394,512) + bf16 hi/mid/lo planes
__global__ __launch_bounds__(256) void k_split_feat(const float* __restrict__ in,
                                                    float* __restrict__ featT,
                                                    unsigned short* __restrict__ FH,
                                                    unsigned short* __restrict__ FM,
                                                    unsigned short* __restrict__ FL) {
    __shared__ float tl[32][33];
    int tx = threadIdx.x & 31, tg = threadIdx.x >> 5;
    int posBase = blockIdx.x * 32, ciBase = blockIdx.y * 32;
#pragma unroll
    for (int j = 0; j < 4; ++j) {
        int ci = ciBase + tg + j * 8;
        int pos = posBase + tx;
        tl[tg + j * 8][tx] = (pos < NPOS) ? in[(size_t)ci * NPOS + pos] : 0.f;
    }
    __syncthreads();
#pragma unroll
    for (int j = 0; j < 4; ++j) {
        int pos = posBase + tg + j * 8;
        int ci = ciBase + tx;
        if (pos < NPOS) {
            float v = tl[tx][tg + j * 8];
            size_t o = (size_t)pos * 512 + ci;
            featT[o] = v;
            unsigned short h = f2bf(v);
            float r1 = v - bf2f(h);
            unsigned short m = f2bf(r1);
            float r2 = r1 - bf2f(m);
            unsigned short l = f2bf(r2);
            FH[o] = h; FM[o] = m; FL[o] = l;
        }
    }
}

// w_rpn (co,ci,3,3) -> Btt[co][p*512+ci] bf16 hi/mid/lo. Also zeroes the verify flag.
__global__ __launch_bounds__(256) void k_prep_w(const float* __restrict__ w,
                                                unsigned short* __restrict__ BH,
                                                unsigned short* __restrict__ BM,
                                                unsigned short* __restrict__ BL,
                                                int* __restrict__ flag) {
    __shared__ float buf[4608];
    int co = blockIdx.x, t = threadIdx.x;
    if (co == 0 && t == 0) flag[0] = 0;
    const float* src = w + (size_t)co * 4608;
    for (int j = t; j < 4608; j += 256) buf[j] = src[j];   // input order (ci,p)
    __syncthreads();
    size_t base = (size_t)co * 4608;
    for (int j = t; j < 4608; j += 256) {                  // output order (p,ci)
        int p = j >> 9, ci = j & 511;
        float v = buf[ci * 9 + p];
        unsigned short h = f2bf(v);
        float r1 = v - bf2f(h);
        unsigned short m = f2bf(r1);
        float r2 = r1 - bf2f(m);
        unsigned short l = f2bf(r2);
        BH[base + j] = h; BM[base + j] = m; BL[base + j] = l;
    }
}

// 3x3 conv as implicit-im2col MFMA GEMM, split-bf16 (HH,HM,MH,HL,LH,MM).
// Block 128 = 2 waves; wave z does K-half of a (16pos x 64co) tile; LDS reduce.
__global__ __launch_bounds__(128) void k_conv_mfma(const unsigned short* __restrict__ FH,
                                                   const unsigned short* __restrict__ FM,
                                                   const unsigned short* __restrict__ FL,
                                                   const unsigned short* __restrict__ BH,
                                                   const unsigned short* __restrict__ BM,
                                                   const unsigned short* __restrict__ BL,
                                                   float* __restrict__ P) {
    __shared__ float red[16 * 64];
    int t = threadIdx.x;
    int z = t >> 6, lane = t & 63;
    int posBase = blockIdx.x * 16, coBase = blockIdx.y * 64;

    f32x4 acc[4];
#pragma unroll
    for (int i = 0; i < 4; ++i)
#pragma unroll
        for (int j = 0; j < 4; ++j) acc[i][j] = 0.f;

    int posA = posBase + (lane & 15);
    int h = posA / 63, w = posA - h * 63;
    int kq = (lane >> 4) * 8;
    bool posOK = posA < NPOS;

    int kc0 = z * 72;
    for (int kc = kc0; kc < kc0 + 72; ++kc) {
        int p = kc >> 4;
        int ci0 = (kc & 15) << 5;
        int kh = p / 3, kw = p - kh * 3;
        int hy = h + kh - 1, wx = w + kw - 1;
        bool ok = posOK && (unsigned)hy < 38u && (unsigned)wx < 63u;
        size_t aoff = ok ? ((size_t)(hy * 63 + wx) * 512 + ci0 + kq) : 0;
        uint4 z4 = make_uint4(0u, 0u, 0u, 0u);
        bf16x8 aH = as_bf8(ok ? *reinterpret_cast<const uint4*>(FH + aoff) : z4);
        bf16x8 aM = as_bf8(ok ? *reinterpret_cast<const uint4*>(FM + aoff) : z4);
        bf16x8 aL = as_bf8(ok ? *reinterpret_cast<const uint4*>(FL + aoff) : z4);
        size_t boffBase = (size_t)kc * 32 + kq;
#pragma unroll
        for (int ct = 0; ct < 4; ++ct) {
            size_t boff = (size_t)(coBase + ct * 16 + (lane & 15)) * KK + boffBase;
            bf16x8 bH = as_bf8(*reinterpret_cast<const uint4*>(BH + boff));
            bf16x8 bM = as_bf8(*reinterpret_cast<const uint4*>(BM + boff));
            bf16x8 bL = as_bf8(*reinterpret_cast<const uint4*>(BL + boff));
            acc[ct] = __builtin_amdgcn_mfma_f32_16x16x32_bf16(aM, bM, acc[ct], 0, 0, 0);
            acc[ct] = __builtin_amdgcn_mfma_f32_16x16x32_bf16(aH, bL, acc[ct], 0, 0, 0);
            acc[ct] = __builtin_amdgcn_mfma_f32_16x16x32_bf16(aL, bH, acc[ct], 0, 0, 0);
            acc[ct] = __builtin_amdgcn_mfma_f32_16x16x32_bf16(aH, bM, acc[ct], 0, 0, 0);
            acc[ct] = __builtin_amdgcn_mfma_f32_16x16x32_bf16(aM, bH, acc[ct], 0, 0, 0);
            acc[ct] = __builtin_amdgcn_mfma_f32_16x16x32_bf16(aH, bH, acc[ct], 0, 0, 0);
        }
    }

    if (z == 1) {
#pragma unroll
        for (int ct = 0; ct < 4; ++ct)
#pragma unroll
            for (int rg = 0; rg < 4; ++rg) {
                int pl = (lane >> 4) * 4 + rg;
                red[pl * 64 + ct * 16 + (lane & 15)] = acc[ct][rg];
            }
    }
    __syncthreads();
    if (z == 0) {
#pragma unroll
        for (int ct = 0; ct < 4; ++ct) {
            int co = coBase + ct * 16 + (lane & 15);
#pragma unroll
            for (int rg = 0; rg < 4; ++rg) {
                int pl = (lane >> 4) * 4 + rg;
                int pos = posBase + pl;
                if (pos < NPOS)
                    P[(size_t)pos * 512 + co] = acc[ct][rg] + red[pl * 64 + ct * 16 + (lane & 15)];
            }
        }
    }
}

// VERIFY: recompute 2400 sampled conv outputs directly from pristine net+w_rpn.
// Grid 150 x block 64; block b checks the 16 positions of MFMA tile b.
__global__ __launch_bounds__(64) void k_verify(const float* __restrict__ net,
                                               const float* __restrict__ wr,
                                               const float* __restrict__ P,
                                               int* __restrict__ flag) {
    int b = blockIdx.x, lane = threadIdx.x;
    for (int i = 0; i < 16; ++i) {
        int pos = b * 16 + i;
        if (pos >= NPOS) break;
        int co = (pos * 37 + i * 101) & 511;
        int h = pos / 63, w0 = pos - h * 63;
        float s = 0.f;
        for (int ci = lane; ci < 512; ci += 64) {
#pragma unroll
            for (int p = 0; p < 9; ++p) {
                int kh = p / 3, kw = p - kh * 3;
                int hy = h + kh - 1, wx = w0 + kw - 1;
                if ((unsigned)hy < 38u && (unsigned)wx < 63u)
                    s += net[(size_t)ci * NPOS + hy * 63 + wx] * wr[(size_t)co * 4608 + ci * 9 + p];
            }
        }
        for (int off = 32; off; off >>= 1) s += __shfl_down(s, off);
        if (lane == 0) {
            float d = P[(size_t)pos * 512 + co];
            if (fabsf(d - s) > 3e-4f * (1.f + fabsf(s))) flag[0] = 1;
        }
    }
}

// FALLBACK vector SGEMM conv (independent of planes: featT fp32 + raw w_rpn).
// Early-exits when flag==0. z=0 stores, z=1 accumulates. Grid (75,8).
__global__ __launch_bounds__(256) void k_conv_fb(const float* __restrict__ featT,
                                                 const float* __restrict__ net,
                                                 const float* __restrict__ wr,
                                                 float* __restrict__ P,
                                                 const int* __restrict__ flag,
                                                 int always, int use_net, int z) {
    if (!always && flag[0] == 0) return;
    __shared__ float As[32][34];
    __shared__ float Bs[32][68];
    int t = threadIdx.x;
    int posBase = blockIdx.x * 32, coBase = blockIdx.y * 64;
    int tx = t & 15, ty = t >> 4;
    float acc[2][4] = {{0.f}};
    int posr = t & 31, kqa = t >> 5;
    int cor = t & 63, wv = t >> 6;
    int pos = posBase + posr;
    int h = pos / 63, w0 = pos - h * 63;
    int kc0 = z * 72;
    for (int kc = kc0; kc < kc0 + 72; ++kc) {
        int p = kc >> 4;
        int ci0 = (kc & 15) << 5;
        int kh = p / 3, kw = p - kh * 3;
        int hy = h + kh - 1, wx = w0 + kw - 1;
        bool ok = (unsigned)hy < 38u && (unsigned)wx < 63u && pos < NPOS;
        float a0 = 0.f, a1 = 0.f, a2 = 0.f, a3 = 0.f;
        if (ok) {
            int pp = hy * 63 + wx;
            int ci = ci0 + kqa * 4;
            if (use_net) {
                a0 = net[(size_t)(ci + 0) * NPOS + pp];
                a1 = net[(size_t)(ci + 1) * NPOS + pp];
                a2 = net[(size_t)(ci + 2) * NPOS + pp];
                a3 = net[(size_t)(ci + 3) * NPOS + pp];
            } else {
                float4 av = *reinterpret_cast<const float4*>(featT + (size_t)pp * 512 + ci);
                a0 = av.x; a1 = av.y; a2 = av.z; a3 = av.w;
            }
        }
        float bvals[8];
        {
            int co = coBase + cor;
            int cib = ci0 + wv * 8;
            const float* wrow = wr + (size_t)co * 4608;
#pragma unroll
            for (int j = 0; j < 8; ++j) bvals[j] = wrow[(cib + j) * 9 + p];
        }
        __syncthreads();
        As[kqa * 4 + 0][posr] = a0; As[kqa * 4 + 1][posr] = a1;
        As[kqa * 4 + 2][posr] = a2; As[kqa * 4 + 3][posr] = a3;
#pragma unroll
        for (int j = 0; j < 8; ++j) Bs[wv * 8 + j][cor] = bvals[j];
        __syncthreads();
#pragma unroll
        for (int k = 0; k < 32; ++k) {
            float2 a2v = *reinterpret_cast<const float2*>(&As[k][ty * 2]);
            float4 b4 = *reinterpret_cast<const float4*>(&Bs[k][tx * 4]);
            float aa[2] = {a2v.x, a2v.y};
            float bb[4] = {b4.x, b4.y, b4.z, b4.w};
#pragma unroll
            for (int i = 0; i < 2; ++i)
#pragma unroll
                for (int jj = 0; jj < 4; ++jj) acc[i][jj] += aa[i] * bb[jj];
        }
    }
#pragma unroll
    for (int i = 0; i < 2; ++i) {
        int opos = posBase + ty * 2 + i;
        if (opos >= NPOS) continue;
#pragma unroll
        for (int jj = 0; jj < 4; ++jj) {
            int co = coBase + tx * 4 + jj;
            size_t o = (size_t)opos * 512 + co;
            if (z == 0) P[o] = acc[i][jj];
            else P[o] += acc[i][jj];
        }
    }
}

// 1x1 heads (fuses conv bias+ReLU) + softmax-prob + decode + clip + sort key.
__global__ __launch_bounds__(256) void k_heads(const float* __restrict__ P,
                                               const float* __restrict__ brpn,
                                               const float* __restrict__ wcls,
                                               const float* __restrict__ bcls,
                                               const float* __restrict__ wbbox,
                                               const float* __restrict__ bbbox,
                                               const float* __restrict__ anchors,
                                               float* __restrict__ proposals,
                                               unsigned long long* __restrict__ keys) {
    __shared__ float x[512];
    __shared__ float part[54][4];
    __shared__ float logit[54];
    int pos = blockIdx.x;
    int t = threadIdx.x;
    {
        float v0 = P[(size_t)pos * 512 + t] + brpn[t];
        float v1 = P[(size_t)pos * 512 + t + 256] + brpn[t + 256];
        x[t] = v0 > 0.f ? v0 : 0.f;
        x[t + 256] = v1 > 0.f ? v1 : 0.f;
    }
    __syncthreads();
    if (t < 216) {
        int o = t >> 2, q = t & 3;
        const float* wr = (o < 18) ? (wcls + o * 512) : (wbbox + (o - 18) * 512);
        float s = 0.f;
        int base = q * 128;
#pragma unroll 4
        for (int k2 = 0; k2 < 128; ++k2) s += x[base + k2] * wr[base + k2];
        part[o][q] = s;
    }
    __syncthreads();
    if (t < 54) {
        float b = (t < 18) ? bcls[t] : bbbox[t - 18];
        logit[t] = part[t][0] + part[t][1] + part[t][2] + part[t][3] + b;
    }
    __syncthreads();
    if (t < 9) {
        int a = t;
        float bg = logit[a], fg = logit[9 + a];
        float score = 1.f / (1.f + expf(bg - fg));
        float dx = logit[18 + 4 * a], dy = logit[19 + 4 * a];
        float dw = logit[20 + 4 * a], dh = logit[21 + 4 * a];
        int idx = pos * 9 + a;
        float ax1 = anchors[idx * 4 + 0], ay1 = anchors[idx * 4 + 1];
        float ax2 = anchors[idx * 4 + 2], ay2 = anchors[idx * 4 + 3];
        float aw = ax2 - ax1 + 1.f, ah = ay2 - ay1 + 1.f;
        float cx = ax1 + 0.5f * aw, cy = ay1 + 0.5f * ah;
        float pcx = dx * aw + cx, pcy = dy * ah + cy;
        float pw = expf(dw) * aw, ph = expf(dh) * ah;
        float x1 = fminf(fmaxf(pcx - 0.5f * pw, 0.f), 999.f);
        float y1 = fminf(fmaxf(pcy - 0.5f * ph, 0.f), 599.f);
        float x2 = fminf(fmaxf(pcx + 0.5f * pw, 0.f), 999.f);
        float y2 = fminf(fmaxf(pcy + 0.5f * ph, 0.f), 599.f);
        proposals[idx * 4 + 0] = x1; proposals[idx * 4 + 1] = y1;
        proposals[idx * 4 + 2] = x2; proposals[idx * 4 + 3] = y2;
        union { float f; unsigned int i; } sv; sv.f = score;
        keys[idx] = (((unsigned long long)sv.i) << 32) |
                    (unsigned long long)(0xFFFFFFFFu - (unsigned)idx);
    }
}

__global__ __launch_bounds__(256) void k_rank_partial(const unsigned long long* __restrict__ keys,
                                                      unsigned int* __restrict__ rpart) {
    __shared__ unsigned long long kc[1024];
    int i = blockIdx.x * 256 + threadIdx.x;
    int q = blockIdx.y;
    unsigned long long myk = (i < NANCH) ? keys[i] : 0xFFFFFFFFFFFFFFFFull;
    int j0 = q * QLEN;
    int j1 = j0 + QLEN; if (j1 > NANCH) j1 = NANCH;
    unsigned int cnt = 0;
    for (int base = j0; base < j1; base += 1024) {
        int nload = j1 - base; if (nload > 1024) nload = 1024;
        __syncthreads();
        for (int u = threadIdx.x; u < 1024; u += 256)
            kc[u] = (base + u < j1) ? keys[base + u] : 0ull;
        __syncthreads();
        for (int u = 0; u < nload; ++u)
            cnt += (kc[u] > myk) ? 1u : 0u;
    }
    if (i < NANCH) rpart[i * NQ + q] = cnt;
}

__global__ void k_zero_sboxes(float* __restrict__ sboxes) {
    int i = blockIdx.x * 256 + threadIdx.x;
    if (i < PRE * 4) sboxes[i] = 0.f;
}

__global__ void k_rank_scatter(const unsigned int* __restrict__ rpart,
                               const float* __restrict__ proposals,
                               float* __restrict__ sboxes) {
    int i = blockIdx.x * 256 + threadIdx.x;
    if (i >= NANCH) return;
    unsigned int r = 0;
#pragma unroll
    for (int q = 0; q < NQ; q++) r += rpart[i * NQ + q];
    if (r < PRE) {
        sboxes[r * 4 + 0] = proposals[i * 4 + 0];
        sboxes[r * 4 + 1] = proposals[i * 4 + 1];
        sboxes[r * 4 + 2] = proposals[i * 4 + 2];
        sboxes[r * 4 + 3] = proposals[i * 4 + 3];
    }
}

__global__ __launch_bounds__(64) void k_nms_mask(const float* __restrict__ sboxes,
                                                 unsigned long long* __restrict__ mask) {
    __shared__ float bx[64][4];
    int ib = blockIdx.x, jb = blockIdx.y;
    int lane = threadIdx.x;
    int j = jb * 64 + lane;
    if (j < PRE) {
        bx[lane][0] = sboxes[j * 4 + 0]; bx[lane][1] = sboxes[j * 4 + 1];
        bx[lane][2] = sboxes[j * 4 + 2]; bx[lane][3] = sboxes[j * 4 + 3];
    } else {
        bx[lane][0] = 3e8f; bx[lane][1] = 3e8f; bx[lane][2] = 3e8f; bx[lane][3] = 3e8f;
    }
    __syncthreads();
    int i = ib * 64 + lane;
    if (i >= PRE) return;
    float x1 = sboxes[i * 4 + 0], y1 = sboxes[i * 4 + 1];
    float x2 = sboxes[i * 4 + 2], y2 = sboxes[i * 4 + 3];
    float ar = (x2 - x1 + 1.f) * (y2 - y1 + 1.f);
    unsigned long long bits = 0;
#pragma unroll 4
    for (int u = 0; u < 64; u++) {
        int j2 = jb * 64 + u;
        float iw = fminf(x2, bx[u][2]) - fmaxf(x1, bx[u][0]) + 1.f;
        float ih = fminf(y2, bx[u][3]) - fmaxf(y1, bx[u][1]) + 1.f;
        iw = fmaxf(iw, 0.f); ih = fmaxf(ih, 0.f);
        float inter = iw * ih;
        float arj = (bx[u][2] - bx[u][0] + 1.f) * (bx[u][3] - bx[u][1] + 1.f);
        float iou = inter / (ar + arj - inter);
        if (iou > 0.7f && j2 > i) bits |= (1ull << u);
    }
    mask[(size_t)i * NWORD + jb] = bits;
}

__global__ __launch_bounds__(64) void k_nms_scan(const unsigned long long* __restrict__ mask,
                                                 int* __restrict__ keep) {
    int lane = threadIdx.x;
    unsigned long long rem0 = 0, rem1 = 0;
    int nk = 0;
    for (int b = 0; b < NWORD && nk < POST; ++b) {
        unsigned long long rm = (b < 64) ? __shfl(rem0, b) : __shfl(rem1, b - 64);
        unsigned long long valid = (b == NWORD - 1) ? ((1ull << 48) - 1) : ~0ull;
        unsigned long long alive = ~rm & valid;
        while (alive) {
            int u = __ffsll((long long)alive) - 1;
            int i = b * 64 + u;
            if (lane == 0) keep[nk] = i;
            ++nk;
            if (nk == POST) break;
            const unsigned long long* row = mask + (size_t)i * NWORD;
            rem0 |= row[lane];
            if (lane < NWORD - 64) rem1 |= row[64 + lane];
            unsigned long long rmb = (b < 64) ? __shfl(rem0, b) : __shfl(rem1, b - 64);
            unsigned long long above = (u == 63) ? 0ull : (~0ull << (u + 1));
            alive = ~rmb & valid & above;
        }
    }
    for (int k2 = nk + lane; k2 < POST; k2 += 64) keep[k2] = PRE - 1;
}

__global__ __launch_bounds__(256) void k_gather_rois(const float* sboxes, const int* keep,
                                                     float* outF) {
    int t = threadIdx.x;
    float4 box[2];
    int nr = 0;
    for (int r = t; r < POST; r += 256) {
        int ki = keep[r];
        if (ki < 0) ki = 0; if (ki > PRE - 1) ki = PRE - 1;
        box[nr++] = *reinterpret_cast<const float4*>(sboxes + ki * 4);
    }
    __syncthreads();
    nr = 0;
    for (int r = t; r < POST; r += 256) {
        float4 b = box[nr++];
#pragma unroll
        for (int cg = 0; cg < 8; ++cg)
            *reinterpret_cast<float4*>(outF + (size_t)(r * 512 + cg * 64) * 49) = b;
    }
}

__global__ __launch_bounds__(256) void k_crop_fast(const float* __restrict__ featT,
                                                   float* out) {
    __shared__ float lds[4][49 * 65];
    int r = blockIdx.x;
    int w = threadIdx.x >> 6, lane = threadIdx.x & 63;
    int cg = blockIdx.y * 4 + w;
    int c = cg * 64 + lane;
    float* chunk = out + (size_t)(r * 512 + cg * 64) * 49;
    const float4 b = *reinterpret_cast<const float4*>(chunk);
    float x1 = b.x, y1 = b.y, x2 = b.z, y2 = b.w;
    float by1 = (y1 / 16.f) / 37.f, bx1 = (x1 / 16.f) / 62.f;
    float by2 = (y2 / 16.f) / 37.f, bx2 = (x2 / 16.f) / 62.f;
    float dyn = by2 - by1, dxn = bx2 - bx1;
    for (int e = 0; e < 49; ++e) {
        int oy = e / 7, ox = e - oy * 7;
        float vv[4];
#pragma unroll
        for (int dy = 0; dy < 2; ++dy) {
            int sy = 2 * oy + dy;
            float ty = (float)sy / 13.f;
            float ys = by1 * 37.f + (ty * dyn) * 37.f;
            float yf = floorf(ys);
            float wy = ys - yf;
            int y0  = (int)fminf(fmaxf(yf, 0.f), 37.f);
            int y1i = (int)fminf(fmaxf(yf + 1.f, 0.f), 37.f);
#pragma unroll
            for (int dxx = 0; dxx < 2; ++dxx) {
                int sx = 2 * ox + dxx;
                float tx = (float)sx / 13.f;
                float xs = bx1 * 62.f + (tx * dxn) * 62.f;
                float xf = floorf(xs);
                float wx = xs - xf;
                int x0  = (int)fminf(fmaxf(xf, 0.f), 62.f);
                int x1i = (int)fminf(fmaxf(xf + 1.f, 0.f), 62.f);
                float f00 = featT[(size_t)(y0 * 63 + x0) * 512 + c];
                float f01 = featT[(size_t)(y0 * 63 + x1i) * 512 + c];
                float f10 = featT[(size_t)(y1i * 63 + x0) * 512 + c];
                float f11 = featT[(size_t)(y1i * 63 + x1i) * 512 + c];
                vv[dy * 2 + dxx] = f00 * (1.f - wy) * (1.f - wx) + f01 * (1.f - wy) * wx +
                                   f10 * wy * (1.f - wx) + f11 * wy * wx;
            }
        }
        lds[w][e * 65 + lane] = fmaxf(fmaxf(vv[0], vv[1]), fmaxf(vv[2], vv[3]));
    }
    __syncthreads();
    for (int i = lane; i < 64 * 49; i += 64) {
        int cl = i / 49, e = i - cl * 49;
        chunk[i] = lds[w][e * 65 + cl];
    }
}

__global__ __launch_bounds__(64) void k_crop_slow(const float* __restrict__ net,
                                                  float* out) {
    int r = blockIdx.x, cg = blockIdx.y;
    int lane = threadIdx.x;
    int c = cg * 64 + lane;
    const float4 b = *reinterpret_cast<const float4*>(out + (size_t)(r * 512 + cg * 64) * 49);
    float x1 = b.x, y1 = b.y, x2 = b.z, y2 = b.w;
    float by1 = (y1 / 16.f) / 37.f, bx1 = (x1 / 16.f) / 62.f;
    float by2 = (y2 / 16.f) / 37.f, bx2 = (x2 / 16.f) / 62.f;
    float dyn = by2 - by1, dxn = bx2 - bx1;
    const float* fc = net + (size_t)c * NPOS;
    float* orow = out + ((size_t)r * 512 + c) * 49;
    for (int e = 0; e < 49; ++e) {
        int oy = e / 7, ox = e - oy * 7;
        float vv[4];
#pragma unroll
        for (int dy = 0; dy < 2; ++dy) {
            int sy = 2 * oy + dy;
            float ty = (float)sy / 13.f;
            float ys = by1 * 37.f + (ty * dyn) * 37.f;
            float yf = floorf(ys);
            float wy = ys - yf;
            int y0  = (int)fminf(fmaxf(yf, 0.f), 37.f);
            int y1i = (int)fminf(fmaxf(yf + 1.f, 0.f), 37.f);
#pragma unroll
            for (int dxx = 0; dxx < 2; ++dxx) {
                int sx = 2 * ox + dxx;
                float tx = (float)sx / 13.f;
                float xs = bx1 * 62.f + (tx * dxn) * 62.f;
                float xf = floorf(xs);
                float wx = xs - xf;
                int x0  = (int)fminf(fmaxf(xf, 0.f), 62.f);
                int x1i = (int)fminf(fmaxf(xf + 1.f, 0.f), 62.f);
                float f00 = fc[y0 * 63 + x0];
                float f01 = fc[y0 * 63 + x1i];
                float f10 = fc[y1i * 63 + x0];
                float f11 = fc[y1i * 63 + x1i];
                vv[dy * 2 + dxx] = f00 * (1.f - wy) * (1.f - wx) + f01 * (1.f - wy) * wx +
                                   f10 * wy * (1.f - wx) + f11 * wy * wx;
            }
        }
        orow[e] = fmaxf(fmaxf(vv[0], vv[1]), fmaxf(vv[2], vv[3]));
    }
}

extern "C" void kernel_launch(void* const* d_in, const int* in_sizes, int n_in,
                              void* d_out, int out_size, void* d_ws, size_t ws_size,
                              hipStream_t stream) {
    auto find = [&](int count, int fallback) {
        for (int i = 0; i < n_in; ++i) if (in_sizes[i] == count) return i;
        return fallback;
    };
    const float* net   = (const float*)d_in[find(NPOS * CIN, 0)];
    const float* wrpn  = (const float*)d_in[find(512 * KK, 1)];
    const float* brpn  = (const float*)d_in[find(512, 2)];
    const float* wcls  = (const float*)d_in[find(18 * 512, 3)];
    const float* bcls  = (const float*)d_in[find(18, 4)];
    const float* wbbox = (const float*)d_in[find(36 * 512, 5)];
    const float* bbbox = (const float*)d_in[find(36, 6)];
    const float* anch  = (const float*)d_in[find(NANCH * 4, 7)];

    char* ob = (char*)d_out;
    float* P                 = (float*)(ob + OFF_P);
    float* sboxes            = (float*)(ob + OFF_SBOX);
    int* keep                = (int*)(ob + OFF_KEEP);
    unsigned short* BH       = (unsigned short*)(ob + OFF_BH);
    unsigned long long* mask = (unsigned long long*)(ob + OFF_MASK);
    unsigned short* BM       = (unsigned short*)(ob + OFF_BM);
    unsigned short* BL       = (unsigned short*)(ob + OFF_BL);
    unsigned short* FH       = (unsigned short*)(ob + OFF_FH);
    unsigned short* FM       = (unsigned short*)(ob + OFF_FM);
    unsigned short* FL       = (unsigned short*)(ob + OFF_FL);
    unsigned long long* keys = (unsigned long long*)(ob + OFF_KEYS);
    float* proposals         = (float*)(ob + OFF_PROP);
    unsigned int* rpart      = (unsigned int*)(ob + OFF_RPART);
    int* flag                = (int*)(ob + OFF_FLAG);
    float* outF              = (float*)d_out;

    const bool ws_ok = (ws_size >= (size_t)FEATT_BYTES);
    float* featT = ws_ok ? (float*)d_ws : (float*)(ob + OFF_P);   // !ws_ok: clobbered later, unused then
    const int always  = ws_ok ? 0 : 1;   // !ws_ok: force vector fallback (reads net directly)
    const int use_net = ws_ok ? 0 : 1;

    hipLaunchKernelGGL(k_split_feat, dim3(75, 16), dim3(256), 0, stream, net, featT, FH, FM, FL);
    hipLaunchKernelGGL(k_prep_w, dim3(512), dim3(256), 0, stream, wrpn, BH, BM, BL, flag);
    hipLaunchKernelGGL(k_conv_mfma, dim3(150, 8), dim3(128), 0, stream, FH, FM, FL, BH, BM, BL, P);
    hipLaunchKernelGGL(k_verify, dim3(150), dim3(64), 0, stream, net, wrpn, P, flag);
    hipLaunchKernelGGL(k_conv_fb, dim3(75, 8), dim3(256), 0, stream, featT, net, wrpn, P, flag, always, use_net, 0);
    hipLaunchKernelGGL(k_conv_fb, dim3(75, 8), dim3(256), 0, stream, featT, net, wrpn, P, flag, always, use_net, 1);
    hipLaunchKernelGGL(k_heads, dim3(NPOS), dim3(256), 0, stream, P, brpn, wcls, bcls, wbbox, bbbox, anch, proposals, keys);
    hipLaunchKernelGGL(k_rank_partial, dim3(85, NQ), dim3(256), 0, stream, keys, rpart);
    hipLaunchKernelGGL(k_zero_sboxes, dim3((PRE * 4 + 255) / 256), dim3(256), 0, stream, sboxes);
    hipLaunchKernelGGL(k_rank_scatter, dim3(85), dim3(256), 0, stream, rpart, proposals, sboxes);
    hipLaunchKernelGGL(k_nms_mask, dim3(NWORD, NWORD), dim3(64), 0, stream, sboxes, mask);
    hipLaunchKernelGGL(k_nms_scan, dim3(1), dim3(64), 0, stream, mask, keep);
    hipLaunchKernelGGL(k_gather_rois, dim3(1), dim3(256), 0, stream, sboxes, keep, outF);
    if (ws_ok)
        hipLaunchKernelGGL(k_crop_fast, dim3(POST, 2), dim3(256), 0, stream, featT, outF);
    else
        hipLaunchKernelGGL(k_crop_slow, dim3(POST, 8), dim3(64), 0, stream, net, outF);
}